// Round 6
// baseline (518.174 us; speedup 1.0000x reference)
//
#include <hip/hip_runtime.h>
#include <hip/hip_bf16.h>
#include <math.h>

typedef float floatx4 __attribute__((ext_vector_type(4)));
typedef short shortx8 __attribute__((ext_vector_type(8)));
typedef unsigned short ush;

// Problem constants
#define NB    2
#define NC    512
#define NL    4096   // H*W
#define NN    1024   // (H/2)*(W/2)
#define NH    8
#define NDK   64
#define NR    63
#define LOG2E 1.44269504f
#define QT_SCALE (1.44269504f/4096.0f)

// ws layout (float offsets); total 9,966,208 f = 39.9 MB
#define OFF_QT     0u          // bf16 qT [b][h][m][d]: 2,097,152 f
#define OFF_T      2097152u    // fp32 t: 1,048,576 f
#define OFF_GS     3145728u    // 128
#define OFF_POS    3145856u    // 4,096
#define OFF_KT     3149952u    // bf16 kT [b][h][j][d]: 524,288 f
#define OFF_VV     3674240u    // bf16 vv [b][c][j]: 524,288 f
#define OFF_SMP    4198528u    // bf16 smp: 524,288 f
#define OFF_WEFF   4722816u    // fp32 W_eff [512][2048]: 1,048,576 f
#define OFF_BEFF   5771392u    // fp32 bias_eff: 512
#define OFF_PART   5771904u    // fp32 part: 4,194,304 f
#define OFF_TAB4   5771904u    // uint2 tab4 (aliases part, after reduce): 65,536 f
#define OFF_AO     5837440u    // bf16 ao (aliases part+64K): 2,097,152 f

__device__ __forceinline__ ush f2bf(float f) {
    unsigned u = __float_as_uint(f);
    u += 0x7fffu + ((u >> 16) & 1u);
    return (ush)(u >> 16);
}
__device__ __forceinline__ float bf2f(ush h) {
    return __uint_as_float(((unsigned)h) << 16);
}

// ---------------------------------------------------------------------------
// Unified bf16-MFMA GEMM:  Y[b][m][p] = (bias[m]) + sum_k A[m][k] * B[b][k][p]
// NP: 1 = plain bf16; 3 = bf16x3 split precision (~fp32 accuracy)
// BSRC: 0 = fp32 [b][K][P]; 1 = fp32 im2col (2x2 s2 conv on [b][512][64][64]);
//       2 = bf16 [b][K][P]
// OUTMODE: 0 = fp32+bias; 2 = fp32 split-K partial (no bias);
//          4 = kv split: m<512 -> kT [b][h][j][d] bf16; m>=512 -> vv [b][c][j] bf16
//          5 = qT only: bf16 [b][h][p][d], scaled by QT_SCALE
// Tile 128m x 64p, BK=64, 4 waves. Fragment map (verified):
// A frag: a[m=l15][k=kk*32+quad*8]; B frag: b[p=l15][k=...]; C: row=quad*4+reg, col=l15.
// ---------------------------------------------------------------------------
template<int NP, int BSRC, int OUTMODE>
__global__ __launch_bounds__(256) void gemm_mfma_k(
    const float* __restrict__ A, const void* __restrict__ Bv,
    const float* __restrict__ bias, void* __restrict__ Yv, void* __restrict__ Y2,
    int M, int K, int P, int KS)
{
    __shared__ ush a_hi[128 * 72];
    __shared__ ush b_hi[64 * 72];
    __shared__ ush a_lo[NP == 3 ? 128 * 72 : 64];
    __shared__ ush b_lo[NP == 3 ? 64 * 72 : 64];

    int tid = threadIdx.x;
    int wv = tid >> 6, lane = tid & 63, quad = lane >> 4, l15 = lane & 15;
    int bz = blockIdx.z;
    int b = bz / KS, ks = bz - b * KS;
    int m0 = blockIdx.y * 128, p0 = blockIdx.x * 64;
    int Ksl = K / KS, kbeg = ks * Ksl;

    floatx4 acc[2][4];
    #pragma unroll
    for (int mt = 0; mt < 2; ++mt)
        #pragma unroll
        for (int pt = 0; pt < 4; ++pt) acc[mt][pt] = (floatx4)0.f;

    for (int kc = 0; kc < Ksl; kc += 64) {
        int kg0 = kbeg + kc;
        #pragma unroll
        for (int r = 0; r < 8; ++r) {
            int idx = r * 256 + tid;
            int m = idx >> 4, k4 = (idx & 15) << 2;
            float4 av = *(const float4*)(A + (size_t)(m0 + m) * K + kg0 + k4);
            int o = m * 72 + k4;
            ush h0 = f2bf(av.x), h1 = f2bf(av.y), h2 = f2bf(av.z), h3 = f2bf(av.w);
            a_hi[o] = h0; a_hi[o + 1] = h1; a_hi[o + 2] = h2; a_hi[o + 3] = h3;
            if (NP == 3) {
                a_lo[o]     = f2bf(av.x - bf2f(h0));
                a_lo[o + 1] = f2bf(av.y - bf2f(h1));
                a_lo[o + 2] = f2bf(av.z - bf2f(h2));
                a_lo[o + 3] = f2bf(av.w - bf2f(h3));
            }
        }
        #pragma unroll
        for (int r = 0; r < 8; ++r) {
            int idx = r * 256 + tid;
            int k = idx >> 5, p2 = (idx & 31) << 1;
            float v0, v1;
            if (BSRC == 0) {
                const float* Bp = (const float*)Bv + (size_t)b * K * P;
                float2 t2 = *(const float2*)(Bp + (size_t)(kg0 + k) * P + p0 + p2);
                v0 = t2.x; v1 = t2.y;
            } else if (BSRC == 1) {
                const float* Bp = (const float*)Bv + (size_t)b * NC * NL;
                int kk = kg0 + k;
                int c = kk >> 2, kh = (kk >> 1) & 1, kw = kk & 1;
                int p = p0 + p2;
                int oh = p >> 5, ow = p & 31;
                const float* base = Bp + (size_t)c * NL + (2 * oh + kh) * 64 + kw;
                v0 = base[2 * ow];
                v1 = base[2 * ow + 2];
            } else {
                const ush* Bp = (const ush*)Bv + (size_t)b * K * P;
                unsigned u = *(const unsigned*)(Bp + (size_t)(kg0 + k) * P + p0 + p2);
                v0 = bf2f((ush)(u & 0xffffu));
                v1 = bf2f((ush)(u >> 16));
            }
            ush h0 = f2bf(v0), h1 = f2bf(v1);
            b_hi[p2 * 72 + k] = h0;
            b_hi[(p2 + 1) * 72 + k] = h1;
            if (NP == 3) {
                b_lo[p2 * 72 + k]       = f2bf(v0 - bf2f(h0));
                b_lo[(p2 + 1) * 72 + k] = f2bf(v1 - bf2f(h1));
            }
        }
        __syncthreads();

        shortx8 ah[2][2], al[2][2];
        #pragma unroll
        for (int mt = 0; mt < 2; ++mt)
            #pragma unroll
            for (int kk = 0; kk < 2; ++kk) {
                int o = (wv * 32 + mt * 16 + l15) * 72 + kk * 32 + quad * 8;
                ah[mt][kk] = *(const shortx8*)&a_hi[o];
                if (NP == 3) al[mt][kk] = *(const shortx8*)&a_lo[o];
            }
        #pragma unroll
        for (int pt = 0; pt < 4; ++pt) {
            #pragma unroll
            for (int kk = 0; kk < 2; ++kk) {
                int o = (pt * 16 + l15) * 72 + kk * 32 + quad * 8;
                shortx8 bh = *(const shortx8*)&b_hi[o];
                acc[0][pt] = __builtin_amdgcn_mfma_f32_16x16x32_bf16(ah[0][kk], bh, acc[0][pt], 0, 0, 0);
                acc[1][pt] = __builtin_amdgcn_mfma_f32_16x16x32_bf16(ah[1][kk], bh, acc[1][pt], 0, 0, 0);
                if (NP == 3) {
                    shortx8 bl = *(const shortx8*)&b_lo[o];
                    acc[0][pt] = __builtin_amdgcn_mfma_f32_16x16x32_bf16(ah[0][kk], bl, acc[0][pt], 0, 0, 0);
                    acc[1][pt] = __builtin_amdgcn_mfma_f32_16x16x32_bf16(ah[1][kk], bl, acc[1][pt], 0, 0, 0);
                    acc[0][pt] = __builtin_amdgcn_mfma_f32_16x16x32_bf16(al[0][kk], bh, acc[0][pt], 0, 0, 0);
                    acc[1][pt] = __builtin_amdgcn_mfma_f32_16x16x32_bf16(al[1][kk], bh, acc[1][pt], 0, 0, 0);
                }
            }
        }
        __syncthreads();
    }

    #pragma unroll
    for (int mt = 0; mt < 2; ++mt) {
        #pragma unroll
        for (int reg = 0; reg < 4; ++reg) {
            int m = m0 + wv * 32 + mt * 16 + quad * 4 + reg;
            float bb = (OUTMODE == 2) ? 0.f : bias[m];
            #pragma unroll
            for (int pt = 0; pt < 4; ++pt) {
                int p = p0 + pt * 16 + l15;
                float val = acc[mt][pt][reg] + bb;
                if (OUTMODE == 0) {
                    ((float*)Yv)[(size_t)b * M * P + (size_t)m * P + p] = val;
                } else if (OUTMODE == 2) {
                    ((float*)Yv)[(size_t)(ks * NB + b) * M * P + (size_t)m * P + p] = val;
                } else if (OUTMODE == 5) {
                    int h = m >> 6, d = m & 63;
                    ((ush*)Yv)[(((size_t)(b * 8 + h) * 4096) + p) * 64 + d] = f2bf(val * QT_SCALE);
                } else { // 4
                    if (m < 512) {
                        int h = m >> 6, d = m & 63;
                        ((ush*)Yv)[(((size_t)(b * 8 + h) * 1024) + p) * 64 + d] = f2bf(val);
                    } else {
                        int c = m - 512;
                        ((ush*)Y2)[((size_t)(b * 512) + c) * 1024 + p] = f2bf(val);
                    }
                }
            }
        }
    }
}

// ---------------------------------------------------------------------------
// W_eff[co][ci*4+khw] = sum_cm off1_w[co][cm][khw] * q_w[cm][ci]  (bf16x3)
// Grid (8, 4, 4): 64p x 128m x khw. K=512 (cm).
// ---------------------------------------------------------------------------
__global__ __launch_bounds__(256) void weff_k(
    const float* __restrict__ off1w, const float* __restrict__ qw,
    float* __restrict__ weff)
{
    __shared__ ush a_hi[128 * 72], a_lo[128 * 72];
    __shared__ ush b_hi[64 * 72],  b_lo[64 * 72];
    int tid = threadIdx.x;
    int wv = tid >> 6, lane = tid & 63, quad = lane >> 4, l15 = lane & 15;
    int khw = blockIdx.z;
    int m0 = blockIdx.y * 128, p0 = blockIdx.x * 64;

    floatx4 acc[2][4];
    #pragma unroll
    for (int mt = 0; mt < 2; ++mt)
        #pragma unroll
        for (int pt = 0; pt < 4; ++pt) acc[mt][pt] = (floatx4)0.f;

    for (int k0 = 0; k0 < 512; k0 += 64) {
        #pragma unroll
        for (int r = 0; r < 32; ++r) {
            int idx = r * 256 + tid;
            int m = idx >> 6, k = idx & 63;
            float v = off1w[((size_t)(m0 + m) * 512 + k0 + k) * 4 + khw];
            ush h = f2bf(v);
            a_hi[m * 72 + k] = h;
            a_lo[m * 72 + k] = f2bf(v - bf2f(h));
        }
        #pragma unroll
        for (int r = 0; r < 8; ++r) {
            int idx = r * 256 + tid;
            int k = idx >> 5, p2 = (idx & 31) << 1;
            float2 t2 = *(const float2*)(qw + (size_t)(k0 + k) * 512 + p0 + p2);
            ush h0 = f2bf(t2.x), h1 = f2bf(t2.y);
            b_hi[p2 * 72 + k] = h0;       b_hi[(p2 + 1) * 72 + k] = h1;
            b_lo[p2 * 72 + k] = f2bf(t2.x - bf2f(h0));
            b_lo[(p2 + 1) * 72 + k] = f2bf(t2.y - bf2f(h1));
        }
        __syncthreads();
        shortx8 ah[2][2], al[2][2];
        #pragma unroll
        for (int mt = 0; mt < 2; ++mt)
            #pragma unroll
            for (int kk = 0; kk < 2; ++kk) {
                int o = (wv * 32 + mt * 16 + l15) * 72 + kk * 32 + quad * 8;
                ah[mt][kk] = *(const shortx8*)&a_hi[o];
                al[mt][kk] = *(const shortx8*)&a_lo[o];
            }
        #pragma unroll
        for (int pt = 0; pt < 4; ++pt) {
            #pragma unroll
            for (int kk = 0; kk < 2; ++kk) {
                int o = (pt * 16 + l15) * 72 + kk * 32 + quad * 8;
                shortx8 bh = *(const shortx8*)&b_hi[o];
                shortx8 bl = *(const shortx8*)&b_lo[o];
                #pragma unroll
                for (int mt = 0; mt < 2; ++mt) {
                    acc[mt][pt] = __builtin_amdgcn_mfma_f32_16x16x32_bf16(ah[mt][kk], bh, acc[mt][pt], 0, 0, 0);
                    acc[mt][pt] = __builtin_amdgcn_mfma_f32_16x16x32_bf16(ah[mt][kk], bl, acc[mt][pt], 0, 0, 0);
                    acc[mt][pt] = __builtin_amdgcn_mfma_f32_16x16x32_bf16(al[mt][kk], bh, acc[mt][pt], 0, 0, 0);
                }
            }
        }
        __syncthreads();
    }
    #pragma unroll
    for (int mt = 0; mt < 2; ++mt)
        #pragma unroll
        for (int reg = 0; reg < 4; ++reg) {
            int m = m0 + wv * 32 + mt * 16 + quad * 4 + reg;
            #pragma unroll
            for (int pt = 0; pt < 4; ++pt) {
                int p = p0 + pt * 16 + l15;
                weff[(size_t)m * 2048 + p * 4 + khw] = acc[mt][pt][reg];
            }
        }
}

// bias_eff[co] = off1_b[co] + sum_cm (sum_khw off1_w[co][cm][khw]) * q_b[cm]
__global__ __launch_bounds__(256) void biaseff_k(const float* __restrict__ off1w,
                                                 const float* __restrict__ off1b,
                                                 const float* __restrict__ qb,
                                                 float* __restrict__ beff)
{
    int co = blockIdx.x * 256 + threadIdx.x;
    float s = off1b[co];
    for (int cm = 0; cm < 512; ++cm) {
        const float* w = off1w + ((size_t)co * 512 + cm) * 4;
        s += (w[0] + w[1] + w[2] + w[3]) * qb[cm];
    }
    beff[co] = s;
}

// ---------------------------------------------------------------------------
__global__ __launch_bounds__(256) void reduce_off1_k(const float* __restrict__ part,
                                                     const float* __restrict__ beff,
                                                     float* __restrict__ t)
{
    int i = blockIdx.x * 256 + threadIdx.x;
    float v = part[i] + part[i + 1048576] + part[i + 2097152] + part[i + 3145728];
    t[i] = v + beff[(i >> 10) & 511];
}

__global__ __launch_bounds__(256) void gn_stats_k(const float* __restrict__ T, float* __restrict__ gs)
{
    int bg = blockIdx.x;
    const float* base = T + (size_t)bg * 16384;
    float s = 0.f, ss = 0.f;
    for (int i = threadIdx.x; i < 16384; i += 256) { float v = base[i]; s += v; ss += v * v; }
    #pragma unroll
    for (int off = 32; off >= 1; off >>= 1) { s += __shfl_xor(s, off); ss += __shfl_xor(ss, off); }
    __shared__ float red[8];
    int wv = threadIdx.x >> 6;
    if ((threadIdx.x & 63) == 0) { red[wv * 2] = s; red[wv * 2 + 1] = ss; }
    __syncthreads();
    if (threadIdx.x == 0) {
        float S = red[0] + red[2] + red[4] + red[6];
        float SS = red[1] + red[3] + red[5] + red[7];
        float mu = S / 16384.f;
        float var = SS / 16384.f - mu * mu;
        gs[bg * 2] = mu;
        gs[bg * 2 + 1] = rsqrtf(var + 1e-5f);
    }
}

__global__ __launch_bounds__(256) void gn_gelu_k(float* __restrict__ T, const float* __restrict__ gs,
                                                 const float* __restrict__ gw, const float* __restrict__ gb)
{
    int idx = blockIdx.x * 256 + threadIdx.x;
    int bg = idx >> 14;
    int c = (idx >> 10) & 511;
    float mu = gs[bg * 2], rs = gs[bg * 2 + 1];
    float v = (T[idx] - mu) * rs * gw[c] + gb[c];
    T[idx] = v * 0.5f * (1.f + erff(v * 0.70710678118654752f));
}

// ---------------------------------------------------------------------------
__global__ __launch_bounds__(256) void offset_pos_k(const float* __restrict__ T,
                                                    const float* __restrict__ w2,
                                                    float* __restrict__ pos)
{
    int b = blockIdx.x >> 5;
    int og = threadIdx.x & 31;
    int cg = threadIdx.x >> 5;
    int op = ((blockIdx.x & 31) << 5) + og;
    const float* Tb = T + (size_t)b * NC * NN + (size_t)cg * 64 * NN + op;
    float o0 = 0.f, o1 = 0.f;
    #pragma unroll 4
    for (int c = 0; c < 64; ++c) {
        float tv = Tb[(size_t)c * NN];
        o0 += w2[cg * 64 + c] * tv;
        o1 += w2[512 + cg * 64 + c] * tv;
    }
    __shared__ float rs[2][8][32];
    rs[0][cg][og] = o0;
    rs[1][cg][og] = o1;
    __syncthreads();
    if (threadIdx.x < 64) {
        int coord = threadIdx.x >> 5, og2 = threadIdx.x & 31;
        float s = 0.f;
        #pragma unroll
        for (int k = 0; k < 8; ++k) s += rs[coord][k][og2];
        int opf = ((blockIdx.x & 31) << 5) + og2;
        int oh = opf >> 5, ow = opf & 31;
        float ref = (coord == 0) ? ((0.5f + oh) / 31.f * 2.f - 1.f)
                                 : ((0.5f + ow) / 31.f * 2.f - 1.f);
        pos[((size_t)b * 1024 + opf) * 2 + coord] = fminf(fmaxf(s + ref, -1.f), 1.f);
    }
}

// ---------------------------------------------------------------------------
__global__ __launch_bounds__(256) void sample_k(const float* __restrict__ x,
                                                const float* __restrict__ pos,
                                                ush* __restrict__ smp)
{
    int idx = blockIdx.x * 256 + threadIdx.x;
    int j = idx & 1023, c = (idx >> 10) & 511, b = idx >> 19;
    float py = pos[(b * 1024 + j) * 2];
    float px = pos[(b * 1024 + j) * 2 + 1];
    float fx = (px + 1.f) * 0.5f * 63.f;
    float fy = (py + 1.f) * 0.5f * 63.f;
    float flx = floorf(fx), fly = floorf(fy);
    float wx = fx - flx, wy = fy - fly;
    int x0 = min(max((int)flx, 0), 63), y0 = min(max((int)fly, 0), 63);
    int x1 = min(x0 + 1, 63),           y1 = min(y0 + 1, 63);
    const float* xb = x + ((size_t)(b * NC + c)) * NL;
    float v00 = xb[y0 * 64 + x0];
    float v01 = xb[y0 * 64 + x1];
    float v10 = xb[y1 * 64 + x0];
    float v11 = xb[y1 * 64 + x1];
    float v = v00 * (1 - wx) * (1 - wy) + v01 * wx * (1 - wy)
            + v10 * (1 - wx) * wy       + v11 * wx * wy;
    smp[idx] = f2bf(v);
}

// ---------------------------------------------------------------------------
__global__ __launch_bounds__(256) void tab4_k(const float* __restrict__ rpe,
                                              uint2* __restrict__ tab4)
{
    int i = blockIdx.x * 256 + threadIdx.x;   // 8*4096
    int h = i >> 12, y = (i >> 6) & 63, x = i & 63;
    const float* R = rpe + (size_t)h * 3969;
    float v00 = (y < 63 && x < 63)         ? R[y * 63 + x] * LOG2E : 0.f;
    float v01 = (y < 63 && x + 1 < 63)     ? R[y * 63 + x + 1] * LOG2E : 0.f;
    float v10 = (y + 1 < 63 && x < 63)     ? R[(y + 1) * 63 + x] * LOG2E : 0.f;
    float v11 = (y + 1 < 63 && x + 1 < 63) ? R[(y + 1) * 63 + x + 1] * LOG2E : 0.f;
    uint2 o;
    o.x = (unsigned)f2bf(v00) | ((unsigned)f2bf(v01) << 16);
    o.y = (unsigned)f2bf(v10) | ((unsigned)f2bf(v11) << 16);
    tab4[i] = o;
}

// ---------------------------------------------------------------------------
// MFMA flash attention. Block = (b,h) x 128-query tile, 8 waves x 16 rows,
// 512 threads, barrier-free j-loop. Q/K/V frags direct from global.
// V frags hoisted before bias VALU to hide L2 latency. LDS 59.4 KB ->
// 2 blocks/CU (16 waves). No online max (logits ~1e-2); exp2-domain.
// ---------------------------------------------------------------------------
__global__ __launch_bounds__(512, 4) void attn_k(
    const ush* __restrict__ qT, const ush* __restrict__ kT,
    const ush* __restrict__ vv, const float* __restrict__ pos,
    const uint2* __restrict__ tab4, ush* __restrict__ ao)
{
    __shared__ __align__(16) char smem[59392];
    ush*   pa     = (ush*)smem;               // [128][72]  18432 B
    uint2* tab_s  = (uint2*)(smem + 18432);   // [64][64]   32768 B
    float* posj15 = (float*)(smem + 51200);   // [1024][2]   8192 B
    float* obuf   = (float*)smem;             // [64][133] epilogue alias

    int bh = blockIdx.y;
    int b = bh >> 3, h = bh & 7;
    int m0 = blockIdx.x * 128;
    int tid = threadIdx.x;
    int wv = tid >> 6, lane = tid & 63, quad = lane >> 4, l15 = lane & 15;

    // Q fragments (global, issue early)
    const ush* qbase = qT + ((size_t)bh * 4096 + m0 + wv * 16 + l15) * 64 + quad * 8;
    shortx8 qf0 = *(const shortx8*)(qbase);
    shortx8 qf1 = *(const shortx8*)(qbase + 32);

    // stage tab4 + pos*15.5
    const uint2* tg = tab4 + (size_t)h * 4096;
    for (int i = tid; i < 4096; i += 512) tab_s[i] = tg[i];
    const float* pb = pos + (size_t)b * 2048;
    for (int i = tid; i < 2048; i += 512) posj15[i] = pb[i] * 15.5f;

    float qy15[4], qx15[4];
    #pragma unroll
    for (int reg = 0; reg < 4; ++reg) {
        int mg = m0 + wv * 16 + quad * 4 + reg;
        qy15[reg] = (float)(mg >> 6) * (31.f / 63.f) + 15.5f;
        qx15[reg] = (float)(mg & 63) * (31.f / 63.f) + 15.5f;
    }

    floatx4 o_acc[4], o_sum;
    #pragma unroll
    for (int dt = 0; dt < 4; ++dt) o_acc[dt] = (floatx4)0.f;
    o_sum = (floatx4)0.f;
    shortx8 vone = {16256, 16256, 16256, 16256, 16256, 16256, 16256, 16256};

    __syncthreads();

    const ush* kbase = kT + (size_t)bh * 1024 * 64;
    const ush* vbase = vv + (size_t)(b * 512 + h * 64) * 1024;

    for (int jc = 0; jc < 16; ++jc) {
        int j0 = jc * 64;
        // ---- QK^T (K frags from global) ----
        floatx4 sacc[4];
        #pragma unroll
        for (int jt = 0; jt < 4; ++jt) sacc[jt] = (floatx4)0.f;
        #pragma unroll
        for (int jt = 0; jt < 4; ++jt) {
            const ush* kp = kbase + (size_t)(j0 + jt * 16 + l15) * 64 + quad * 8;
            shortx8 kf0 = *(const shortx8*)kp;
            shortx8 kf1 = *(const shortx8*)(kp + 32);
            sacc[jt] = __builtin_amdgcn_mfma_f32_16x16x32_bf16(qf0, kf0, sacc[jt], 0, 0, 0);
            sacc[jt] = __builtin_amdgcn_mfma_f32_16x16x32_bf16(qf1, kf1, sacc[jt], 0, 0, 0);
        }
        // ---- V prefetch (latency hidden behind bias VALU) ----
        shortx8 vf0[4], vf1[4];
        #pragma unroll
        for (int dt = 0; dt < 4; ++dt) {
            const ush* vp = vbase + (size_t)(dt * 16 + l15) * 1024 + j0 + quad * 8;
            vf0[dt] = *(const shortx8*)vp;
            vf1[dt] = *(const shortx8*)(vp + 32);
        }
        // ---- bias (1 LDS b64/eval) + exp2 + P write ----
        #pragma unroll
        for (int jt = 0; jt < 4; ++jt) {
            int j = j0 + jt * 16 + l15;
            float2 pp = *(const float2*)&posj15[j * 2];
            #pragma unroll
            for (int reg = 0; reg < 4; ++reg) {
                float gy = qy15[reg] - pp.x;
                float gx = qx15[reg] - pp.y;
                float fy = floorf(gy), fx = floorf(gx);
                float wy = gy - fy, wx = gx - fx;
                int y0 = min(max((int)fy, 0), 62);
                int x0 = min(max((int)fx, 0), 62);
                uint2 tw = tab_s[(y0 << 6) + x0];
                float r00 = __uint_as_float(tw.x << 16);
                float r01 = __uint_as_float(tw.x & 0xffff0000u);
                float r10 = __uint_as_float(tw.y << 16);
                float r11 = __uint_as_float(tw.y & 0xffff0000u);
                float bx0 = r00 + wx * (r01 - r00);
                float bx1 = r10 + wx * (r11 - r10);
                float p = exp2f(sacc[jt][reg] + (bx0 + wy * (bx1 - bx0)));
                pa[(wv * 16 + quad * 4 + reg) * 72 + jt * 16 + l15] = f2bf(p);
            }
        }
        // ---- PV + denom (wave-private P roundtrip, no barrier) ----
        const ush* pbase = pa + (wv * 16 + l15) * 72 + quad * 8;
        shortx8 pf0 = *(const shortx8*)pbase;
        shortx8 pf1 = *(const shortx8*)(pbase + 32);
        o_sum = __builtin_amdgcn_mfma_f32_16x16x32_bf16(pf0, vone, o_sum, 0, 0, 0);
        o_sum = __builtin_amdgcn_mfma_f32_16x16x32_bf16(pf1, vone, o_sum, 0, 0, 0);
        #pragma unroll
        for (int dt = 0; dt < 4; ++dt) {
            o_acc[dt] = __builtin_amdgcn_mfma_f32_16x16x32_bf16(pf0, vf0[dt], o_acc[dt], 0, 0, 0);
            o_acc[dt] = __builtin_amdgcn_mfma_f32_16x16x32_bf16(pf1, vf1[dt], o_acc[dt], 0, 0, 0);
        }
    }

    // ---- epilogue: divide by denom, transpose via LDS, coalesced bf16 store ----
    __syncthreads();
    float inv[4];
    #pragma unroll
    for (int reg = 0; reg < 4; ++reg) inv[reg] = 1.f / o_sum[reg];
    #pragma unroll
    for (int dt = 0; dt < 4; ++dt)
        #pragma unroll
        for (int reg = 0; reg < 4; ++reg)
            obuf[(dt * 16 + l15) * 133 + wv * 16 + quad * 4 + reg] = o_acc[dt][reg] * inv[reg];
    __syncthreads();
    ush* aobase = ao + ((size_t)(b * 512 + h * 64)) * 4096 + m0;
    for (int i = tid; i < 8192; i += 512) {
        int d = i >> 7, m = i & 127;
        aobase[(size_t)d * 4096 + m] = f2bf(obuf[d * 133 + m]);
    }
}

// ---------------------------------------------------------------------------
extern "C" void kernel_launch(void* const* d_in, const int* in_sizes, int n_in,
                              void* d_out, int out_size, void* d_ws, size_t ws_size,
                              hipStream_t stream) {
    const float* x      = (const float*)d_in[0];
    const float* q_w    = (const float*)d_in[1];
    const float* q_b    = (const float*)d_in[2];
    const float* kv_w   = (const float*)d_in[3];
    const float* kv_b   = (const float*)d_in[4];
    const float* off1_w = (const float*)d_in[5];
    const float* off1_b = (const float*)d_in[6];
    const float* gn_w   = (const float*)d_in[7];
    const float* gn_b   = (const float*)d_in[8];
    const float* off2_w = (const float*)d_in[9];
    const float* rpe    = (const float*)d_in[10];
    const float* proj_w = (const float*)d_in[11];
    const float* proj_b = (const float*)d_in[12];

    float* ws   = (float*)d_ws;
    ush*   qT   = (ush*)(ws + OFF_QT);
    float* t    = ws + OFF_T;
    float* gs   = ws + OFF_GS;
    float* pos  = ws + OFF_POS;
    ush*   kT   = (ush*)(ws + OFF_KT);
    ush*   vv   = (ush*)(ws + OFF_VV);
    ush*   smp  = (ush*)(ws + OFF_SMP);
    float* weff = ws + OFF_WEFF;
    float* beff = ws + OFF_BEFF;
    float* part = ws + OFF_PART;
    uint2* tab4 = (uint2*)(ws + OFF_TAB4);
    ush*   ao   = (ush*)(ws + OFF_AO);
    float* out  = (float*)d_out;

    // W_eff = off1_w ∘ q_w (bf16x3), bias_eff
    weff_k<<<dim3(8, 4, 4), 256, 0, stream>>>(off1_w, q_w, weff);
    biaseff_k<<<2, 256, 0, stream>>>(off1_w, off1_b, q_b, beff);
    // qT = bf16(q_w·x + q_b) transposed+scaled (plain bf16 — qT is bf16 anyway)
    gemm_mfma_k<1, 0, 5><<<dim3(64, 4, 2), 256, 0, stream>>>(q_w, x, q_b, qT, nullptr, 512, 512, 4096, 1);
    // t = W_eff ⊛ im2col(x): bf16x3, split-K=4  (q fp32 never materialized)
    gemm_mfma_k<3, 1, 2><<<dim3(16, 4, 8), 256, 0, stream>>>(weff, x, nullptr, part, nullptr, 512, 2048, 1024, 4);
    reduce_off1_k<<<4096, 256, 0, stream>>>(part, beff, t);
    // GroupNorm + GELU
    gn_stats_k<<<64, 256, 0, stream>>>(t, gs);
    gn_gelu_k<<<4096, 256, 0, stream>>>(t, gs, gn_w, gn_b);
    // offsets -> sampling positions (fp32)
    offset_pos_k<<<64, 256, 0, stream>>>(t, off2_w, pos);
    // bias table (part dead; tab4/ao alias it)
    tab4_k<<<128, 256, 0, stream>>>(rpe, tab4);
    // bilinear sample -> bf16
    sample_k<<<4096, 256, 0, stream>>>(x, pos, smp);
    // kv = 1x1 conv(sampled): plain bf16 -> kT (transposed) + vv
    gemm_mfma_k<1, 2, 4><<<dim3(16, 8, 2), 256, 0, stream>>>(kv_w, smp, kv_b, kT, vv, 1024, 512, 1024, 1);
    // fused MFMA flash attention -> bf16 ao
    attn_k<<<dim3(32, 16), 512, 0, stream>>>(qT, kT, vv, pos, tab4, ao);
    // final projection: plain bf16, fp32 out
    gemm_mfma_k<1, 2, 0><<<dim3(64, 4, 2), 256, 0, stream>>>(proj_w, ao, proj_b, out, nullptr, 512, 512, 4096, 1);
}

// Round 7
// 399.566 us; speedup vs baseline: 1.2968x; 1.2968x over previous
//
#include <hip/hip_runtime.h>
#include <hip/hip_bf16.h>
#include <hip/hip_fp16.h>
#include <math.h>

typedef float floatx4 __attribute__((ext_vector_type(4)));
typedef short shortx8 __attribute__((ext_vector_type(8)));
typedef unsigned short ush;

// Problem constants
#define NB    2
#define NC    512
#define NL    4096   // H*W
#define NN    1024   // (H/2)*(W/2)
#define NH    8
#define NDK   64
#define NR    63
#define LOG2E 1.44269504f
#define QT_SCALE (1.44269504f/4096.0f)

// ws layout (float offsets)
#define OFF_QT     0u          // bf16 qT [b][h][m][d]: 2,097,152 f
#define OFF_T      2097152u    // fp32 t: 1,048,576 f
#define OFF_GS     3145728u    // 128
#define OFF_POS    3145856u    // 4,096
#define OFF_KT     3149952u    // bf16 kT [b][h][j][d]: 524,288 f
#define OFF_VV     3674240u    // bf16 vv [b][c][j]: 524,288 f
#define OFF_SMP    4198528u    // bf16 smp: 524,288 f
#define OFF_WEFF   4722816u    // fp32 W_eff [512][2048]: 1,048,576 f
#define OFF_BEFF   5771392u    // fp32 bias_eff: 512
#define OFF_PART   5771904u    // fp32 part: 4,194,304 f
#define OFF_AO     5771904u    // bf16 ao (aliases part; part dead first): 2,097,152 f

__device__ __forceinline__ ush f2bf(float f) {
    unsigned u = __float_as_uint(f);
    u += 0x7fffu + ((u >> 16) & 1u);
    return (ush)(u >> 16);
}
__device__ __forceinline__ float bf2f(ush h) {
    return __uint_as_float(((unsigned)h) << 16);
}

// ---------------------------------------------------------------------------
// Unified bf16-MFMA GEMM:  Y[b][m][p] = (bias[m]) + sum_k A[m][k] * B[b][k][p]
// NP: 1 = plain bf16; 3 = bf16x3 split precision (~fp32 accuracy)
// BSRC: 0 = fp32 [b][K][P]; 1 = fp32 im2col (2x2 s2 conv on [b][512][64][64]);
//       2 = bf16 [b][K][P]
// OUTMODE: 0 = fp32+bias; 2 = fp32 split-K partial (no bias);
//          4 = kv split: m<512 -> kT [b][h][j][d] bf16; m>=512 -> vv [b][c][j] bf16
//          5 = qT only: bf16 [b][h][p][d], scaled by QT_SCALE
// ---------------------------------------------------------------------------
template<int NP, int BSRC, int OUTMODE>
__global__ __launch_bounds__(256) void gemm_mfma_k(
    const float* __restrict__ A, const void* __restrict__ Bv,
    const float* __restrict__ bias, void* __restrict__ Yv, void* __restrict__ Y2,
    int M, int K, int P, int KS)
{
    __shared__ ush a_hi[128 * 72];
    __shared__ ush b_hi[64 * 72];
    __shared__ ush a_lo[NP == 3 ? 128 * 72 : 64];
    __shared__ ush b_lo[NP == 3 ? 64 * 72 : 64];

    int tid = threadIdx.x;
    int wv = tid >> 6, lane = tid & 63, quad = lane >> 4, l15 = lane & 15;
    int bz = blockIdx.z;
    int b = bz / KS, ks = bz - b * KS;
    int m0 = blockIdx.y * 128, p0 = blockIdx.x * 64;
    int Ksl = K / KS, kbeg = ks * Ksl;

    floatx4 acc[2][4];
    #pragma unroll
    for (int mt = 0; mt < 2; ++mt)
        #pragma unroll
        for (int pt = 0; pt < 4; ++pt) acc[mt][pt] = (floatx4)0.f;

    for (int kc = 0; kc < Ksl; kc += 64) {
        int kg0 = kbeg + kc;
        #pragma unroll
        for (int r = 0; r < 8; ++r) {
            int idx = r * 256 + tid;
            int m = idx >> 4, k4 = (idx & 15) << 2;
            float4 av = *(const float4*)(A + (size_t)(m0 + m) * K + kg0 + k4);
            int o = m * 72 + k4;
            ush h0 = f2bf(av.x), h1 = f2bf(av.y), h2 = f2bf(av.z), h3 = f2bf(av.w);
            a_hi[o] = h0; a_hi[o + 1] = h1; a_hi[o + 2] = h2; a_hi[o + 3] = h3;
            if (NP == 3) {
                a_lo[o]     = f2bf(av.x - bf2f(h0));
                a_lo[o + 1] = f2bf(av.y - bf2f(h1));
                a_lo[o + 2] = f2bf(av.z - bf2f(h2));
                a_lo[o + 3] = f2bf(av.w - bf2f(h3));
            }
        }
        #pragma unroll
        for (int r = 0; r < 8; ++r) {
            int idx = r * 256 + tid;
            int k = idx >> 5, p2 = (idx & 31) << 1;
            float v0, v1;
            if (BSRC == 0) {
                const float* Bp = (const float*)Bv + (size_t)b * K * P;
                float2 t2 = *(const float2*)(Bp + (size_t)(kg0 + k) * P + p0 + p2);
                v0 = t2.x; v1 = t2.y;
            } else if (BSRC == 1) {
                const float* Bp = (const float*)Bv + (size_t)b * NC * NL;
                int kk = kg0 + k;
                int c = kk >> 2, kh = (kk >> 1) & 1, kw = kk & 1;
                int p = p0 + p2;
                int oh = p >> 5, ow = p & 31;
                const float* base = Bp + (size_t)c * NL + (2 * oh + kh) * 64 + kw;
                v0 = base[2 * ow];
                v1 = base[2 * ow + 2];
            } else {
                const ush* Bp = (const ush*)Bv + (size_t)b * K * P;
                unsigned u = *(const unsigned*)(Bp + (size_t)(kg0 + k) * P + p0 + p2);
                v0 = bf2f((ush)(u & 0xffffu));
                v1 = bf2f((ush)(u >> 16));
            }
            ush h0 = f2bf(v0), h1 = f2bf(v1);
            b_hi[p2 * 72 + k] = h0;
            b_hi[(p2 + 1) * 72 + k] = h1;
            if (NP == 3) {
                b_lo[p2 * 72 + k]       = f2bf(v0 - bf2f(h0));
                b_lo[(p2 + 1) * 72 + k] = f2bf(v1 - bf2f(h1));
            }
        }
        __syncthreads();

        shortx8 ah[2][2], al[2][2];
        #pragma unroll
        for (int mt = 0; mt < 2; ++mt)
            #pragma unroll
            for (int kk = 0; kk < 2; ++kk) {
                int o = (wv * 32 + mt * 16 + l15) * 72 + kk * 32 + quad * 8;
                ah[mt][kk] = *(const shortx8*)&a_hi[o];
                if (NP == 3) al[mt][kk] = *(const shortx8*)&a_lo[o];
            }
        #pragma unroll
        for (int pt = 0; pt < 4; ++pt) {
            #pragma unroll
            for (int kk = 0; kk < 2; ++kk) {
                int o = (pt * 16 + l15) * 72 + kk * 32 + quad * 8;
                shortx8 bh = *(const shortx8*)&b_hi[o];
                acc[0][pt] = __builtin_amdgcn_mfma_f32_16x16x32_bf16(ah[0][kk], bh, acc[0][pt], 0, 0, 0);
                acc[1][pt] = __builtin_amdgcn_mfma_f32_16x16x32_bf16(ah[1][kk], bh, acc[1][pt], 0, 0, 0);
                if (NP == 3) {
                    shortx8 bl = *(const shortx8*)&b_lo[o];
                    acc[0][pt] = __builtin_amdgcn_mfma_f32_16x16x32_bf16(ah[0][kk], bl, acc[0][pt], 0, 0, 0);
                    acc[1][pt] = __builtin_amdgcn_mfma_f32_16x16x32_bf16(ah[1][kk], bl, acc[1][pt], 0, 0, 0);
                    acc[0][pt] = __builtin_amdgcn_mfma_f32_16x16x32_bf16(al[0][kk], bh, acc[0][pt], 0, 0, 0);
                    acc[1][pt] = __builtin_amdgcn_mfma_f32_16x16x32_bf16(al[1][kk], bh, acc[1][pt], 0, 0, 0);
                }
            }
        }
        __syncthreads();
    }

    #pragma unroll
    for (int mt = 0; mt < 2; ++mt) {
        #pragma unroll
        for (int reg = 0; reg < 4; ++reg) {
            int m = m0 + wv * 32 + mt * 16 + quad * 4 + reg;
            float bb = (OUTMODE == 2) ? 0.f : bias[m];
            #pragma unroll
            for (int pt = 0; pt < 4; ++pt) {
                int p = p0 + pt * 16 + l15;
                float val = acc[mt][pt][reg] + bb;
                if (OUTMODE == 0) {
                    ((float*)Yv)[(size_t)b * M * P + (size_t)m * P + p] = val;
                } else if (OUTMODE == 2) {
                    ((float*)Yv)[(size_t)(ks * NB + b) * M * P + (size_t)m * P + p] = val;
                } else if (OUTMODE == 5) {
                    int h = m >> 6, d = m & 63;
                    ((ush*)Yv)[(((size_t)(b * 8 + h) * 4096) + p) * 64 + d] = f2bf(val * QT_SCALE);
                } else { // 4
                    if (m < 512) {
                        int h = m >> 6, d = m & 63;
                        ((ush*)Yv)[(((size_t)(b * 8 + h) * 1024) + p) * 64 + d] = f2bf(val);
                    } else {
                        int c = m - 512;
                        ((ush*)Y2)[((size_t)(b * 512) + c) * 1024 + p] = f2bf(val);
                    }
                }
            }
        }
    }
}

// ---------------------------------------------------------------------------
// W_eff[co][ci*4+khw] = sum_cm off1_w[co][cm][khw] * q_w[cm][ci]
// GEMV-style: block = 4 co x 256 ci; off1_w reads are block-uniform (s_load),
// q_w reads coalesced; no barriers. Grid (2, 128).
// ---------------------------------------------------------------------------
__global__ __launch_bounds__(256) void weff_k(
    const float* __restrict__ off1w, const float* __restrict__ qw,
    float* __restrict__ weff)
{
    int ci = blockIdx.x * 256 + threadIdx.x;
    int co0 = blockIdx.y * 4;
    float acc[4][4] = {};
    #pragma unroll 4
    for (int cm = 0; cm < 512; ++cm) {
        float qv = qw[(size_t)cm * 512 + ci];
        #pragma unroll
        for (int c = 0; c < 4; ++c) {
            float4 w4 = *(const float4*)(off1w + ((size_t)(co0 + c) * 512 + cm) * 4);
            acc[c][0] += w4.x * qv;
            acc[c][1] += w4.y * qv;
            acc[c][2] += w4.z * qv;
            acc[c][3] += w4.w * qv;
        }
    }
    #pragma unroll
    for (int c = 0; c < 4; ++c)
        #pragma unroll
        for (int khw = 0; khw < 4; ++khw)
            weff[(size_t)(co0 + c) * 2048 + ci * 4 + khw] = acc[c][khw];
}

// bias_eff[co] = off1_b[co] + sum_cm (sum_khw off1_w[co][cm][khw]) * q_b[cm]
// One block per co, 256 threads, block reduce.
__global__ __launch_bounds__(256) void biaseff_k(const float* __restrict__ off1w,
                                                 const float* __restrict__ off1b,
                                                 const float* __restrict__ qb,
                                                 float* __restrict__ beff)
{
    int co = blockIdx.x;
    int tid = threadIdx.x;
    float s = 0.f;
    #pragma unroll
    for (int r = 0; r < 2; ++r) {
        int cm = r * 256 + tid;
        float4 w = *(const float4*)(off1w + ((size_t)co * 512 + cm) * 4);
        s += (w.x + w.y + w.z + w.w) * qb[cm];
    }
    #pragma unroll
    for (int off = 32; off >= 1; off >>= 1) s += __shfl_xor(s, off);
    __shared__ float red[4];
    if ((tid & 63) == 0) red[tid >> 6] = s;
    __syncthreads();
    if (tid == 0) beff[co] = off1b[co] + red[0] + red[1] + red[2] + red[3];
}

// ---------------------------------------------------------------------------
__global__ __launch_bounds__(256) void reduce_off1_k(const float* __restrict__ part,
                                                     const float* __restrict__ beff,
                                                     float* __restrict__ t)
{
    int i = blockIdx.x * 256 + threadIdx.x;
    float v = part[i] + part[i + 1048576] + part[i + 2097152] + part[i + 3145728];
    t[i] = v + beff[(i >> 10) & 511];
}

__global__ __launch_bounds__(256) void gn_stats_k(const float* __restrict__ T, float* __restrict__ gs)
{
    int bg = blockIdx.x;
    const float* base = T + (size_t)bg * 16384;
    float s = 0.f, ss = 0.f;
    for (int i = threadIdx.x; i < 16384; i += 256) { float v = base[i]; s += v; ss += v * v; }
    #pragma unroll
    for (int off = 32; off >= 1; off >>= 1) { s += __shfl_xor(s, off); ss += __shfl_xor(ss, off); }
    __shared__ float red[8];
    int wv = threadIdx.x >> 6;
    if ((threadIdx.x & 63) == 0) { red[wv * 2] = s; red[wv * 2 + 1] = ss; }
    __syncthreads();
    if (threadIdx.x == 0) {
        float S = red[0] + red[2] + red[4] + red[6];
        float SS = red[1] + red[3] + red[5] + red[7];
        float mu = S / 16384.f;
        float var = SS / 16384.f - mu * mu;
        gs[bg * 2] = mu;
        gs[bg * 2 + 1] = rsqrtf(var + 1e-5f);
    }
}

__global__ __launch_bounds__(256) void gn_gelu_k(float* __restrict__ T, const float* __restrict__ gs,
                                                 const float* __restrict__ gw, const float* __restrict__ gb)
{
    int idx = blockIdx.x * 256 + threadIdx.x;
    int bg = idx >> 14;
    int c = (idx >> 10) & 511;
    float mu = gs[bg * 2], rs = gs[bg * 2 + 1];
    float v = (T[idx] - mu) * rs * gw[c] + gb[c];
    T[idx] = v * 0.5f * (1.f + erff(v * 0.70710678118654752f));
}

// ---------------------------------------------------------------------------
__global__ __launch_bounds__(256) void offset_pos_k(const float* __restrict__ T,
                                                    const float* __restrict__ w2,
                                                    float* __restrict__ pos)
{
    int b = blockIdx.x >> 5;
    int og = threadIdx.x & 31;
    int cg = threadIdx.x >> 5;
    int op = ((blockIdx.x & 31) << 5) + og;
    const float* Tb = T + (size_t)b * NC * NN + (size_t)cg * 64 * NN + op;
    float o0 = 0.f, o1 = 0.f;
    #pragma unroll 4
    for (int c = 0; c < 64; ++c) {
        float tv = Tb[(size_t)c * NN];
        o0 += w2[cg * 64 + c] * tv;
        o1 += w2[512 + cg * 64 + c] * tv;
    }
    __shared__ float rs[2][8][32];
    rs[0][cg][og] = o0;
    rs[1][cg][og] = o1;
    __syncthreads();
    if (threadIdx.x < 64) {
        int coord = threadIdx.x >> 5, og2 = threadIdx.x & 31;
        float s = 0.f;
        #pragma unroll
        for (int k = 0; k < 8; ++k) s += rs[coord][k][og2];
        int opf = ((blockIdx.x & 31) << 5) + og2;
        int oh = opf >> 5, ow = opf & 31;
        float ref = (coord == 0) ? ((0.5f + oh) / 31.f * 2.f - 1.f)
                                 : ((0.5f + ow) / 31.f * 2.f - 1.f);
        pos[((size_t)b * 1024 + opf) * 2 + coord] = fminf(fmaxf(s + ref, -1.f), 1.f);
    }
}

// ---------------------------------------------------------------------------
__global__ __launch_bounds__(256) void sample_k(const float* __restrict__ x,
                                                const float* __restrict__ pos,
                                                ush* __restrict__ smp)
{
    int idx = blockIdx.x * 256 + threadIdx.x;
    int j = idx & 1023, c = (idx >> 10) & 511, b = idx >> 19;
    float py = pos[(b * 1024 + j) * 2];
    float px = pos[(b * 1024 + j) * 2 + 1];
    float fx = (px + 1.f) * 0.5f * 63.f;
    float fy = (py + 1.f) * 0.5f * 63.f;
    float flx = floorf(fx), fly = floorf(fy);
    float wx = fx - flx, wy = fy - fly;
    int x0 = min(max((int)flx, 0), 63), y0 = min(max((int)fly, 0), 63);
    int x1 = min(x0 + 1, 63),           y1 = min(y0 + 1, 63);
    const float* xb = x + ((size_t)(b * NC + c)) * NL;
    float v00 = xb[y0 * 64 + x0];
    float v01 = xb[y0 * 64 + x1];
    float v10 = xb[y1 * 64 + x0];
    float v11 = xb[y1 * 64 + x1];
    float v = v00 * (1 - wx) * (1 - wy) + v01 * wx * (1 - wy)
            + v10 * (1 - wx) * wy       + v11 * wx * wy;
    smp[idx] = f2bf(v);
}

// ---------------------------------------------------------------------------
// MFMA flash attention. Block = (b,h) x 128-query tile, 8 waves x 16 rows,
// 512 threads, barrier-free j-loop. Q/K/V frags direct from global.
// LDS 38.9 KB -> 4 blocks/CU (32 waves). Bias table as row-pair packed bf16
// (2 aligned b32 reads/eval); posj in half2. No online max; exp2-domain.
// ---------------------------------------------------------------------------
__global__ __launch_bounds__(512, 4) void attn_k(
    const ush* __restrict__ qT, const ush* __restrict__ kT,
    const ush* __restrict__ vv, const float* __restrict__ pos,
    const float* __restrict__ rpe, ush* __restrict__ ao)
{
    __shared__ __align__(16) char smem[38912];
    ush*      pa     = (ush*)smem;               // [128][72]   18432 B
    unsigned* tab2_s = (unsigned*)(smem + 18432);// [64][64]    16384 B
    __half2*  posj_h = (__half2*)(smem + 34816); // [1024]       4096 B
    ush*      obuf   = (ush*)smem;               // [64][136] epilogue alias

    int bh = blockIdx.y;
    int b = bh >> 3, h = bh & 7;
    int m0 = blockIdx.x * 128;
    int tid = threadIdx.x;
    int wv = tid >> 6, lane = tid & 63, quad = lane >> 4, l15 = lane & 15;

    // Q fragments (global, issue early)
    const ush* qbase = qT + ((size_t)bh * 4096 + m0 + wv * 16 + l15) * 64 + quad * 8;
    shortx8 qf0 = *(const shortx8*)(qbase);
    shortx8 qf1 = *(const shortx8*)(qbase + 32);

    // stage tab2 (row-pair packed bf16 of rpe*log2e, 64x64 zero-padded)
    const float* R = rpe + (size_t)h * (NR * NR);
    for (int i = tid; i < 4096; i += 512) {
        int y = i >> 6, xx = i & 63;
        float a = (y < NR && xx < NR)     ? R[y * NR + xx] * LOG2E : 0.f;
        float bv = (y < NR && xx + 1 < NR) ? R[y * NR + xx + 1] * LOG2E : 0.f;
        tab2_s[i] = (unsigned)f2bf(a) | ((unsigned)f2bf(bv) << 16);
    }
    // stage pos*15.5 as half2
    const float2* pb = (const float2*)(pos + (size_t)b * 2048);
    for (int i = tid; i < 1024; i += 512) {
        float2 p = pb[i];
        posj_h[i] = __floats2half2_rn(p.x * 15.5f, p.y * 15.5f);
    }

    float qy15[4], qx15[4];
    #pragma unroll
    for (int reg = 0; reg < 4; ++reg) {
        int mg = m0 + wv * 16 + quad * 4 + reg;
        qy15[reg] = (float)(mg >> 6) * (31.f / 63.f) + 15.5f;
        qx15[reg] = (float)(mg & 63) * (31.f / 63.f) + 15.5f;
    }

    floatx4 o_acc[4], o_sum;
    #pragma unroll
    for (int dt = 0; dt < 4; ++dt) o_acc[dt] = (floatx4)0.f;
    o_sum = (floatx4)0.f;
    shortx8 vone = {16256, 16256, 16256, 16256, 16256, 16256, 16256, 16256};

    __syncthreads();

    const ush* kbase = kT + (size_t)bh * 1024 * 64;
    const ush* vbase = vv + (size_t)(b * 512 + h * 64) * 1024;

    for (int jc = 0; jc < 16; ++jc) {
        int j0 = jc * 64;
        // ---- QK^T (K frags from global) ----
        floatx4 sacc[4];
        #pragma unroll
        for (int jt = 0; jt < 4; ++jt) sacc[jt] = (floatx4)0.f;
        #pragma unroll
        for (int jt = 0; jt < 4; ++jt) {
            const ush* kp = kbase + (size_t)(j0 + jt * 16 + l15) * 64 + quad * 8;
            shortx8 kf0 = *(const shortx8*)kp;
            shortx8 kf1 = *(const shortx8*)(kp + 32);
            sacc[jt] = __builtin_amdgcn_mfma_f32_16x16x32_bf16(qf0, kf0, sacc[jt], 0, 0, 0);
            sacc[jt] = __builtin_amdgcn_mfma_f32_16x16x32_bf16(qf1, kf1, sacc[jt], 0, 0, 0);
        }
        // ---- V prefetch (latency hidden behind bias VALU) ----
        shortx8 vf0[4], vf1[4];
        #pragma unroll
        for (int dt = 0; dt < 4; ++dt) {
            const ush* vp = vbase + (size_t)(dt * 16 + l15) * 1024 + j0 + quad * 8;
            vf0[dt] = *(const shortx8*)vp;
            vf1[dt] = *(const shortx8*)(vp + 32);
        }
        // ---- bias (2 aligned b32 reads/eval) + exp2 + P write ----
        #pragma unroll
        for (int jt = 0; jt < 4; ++jt) {
            int j = j0 + jt * 16 + l15;
            float2 pp = __half22float2(posj_h[j]);
            #pragma unroll
            for (int reg = 0; reg < 4; ++reg) {
                float gy = qy15[reg] - pp.x;
                float gx = qx15[reg] - pp.y;
                float fy = floorf(gy), fx = floorf(gx);
                float wy = gy - fy, wx = gx - fx;
                int y0 = min(max((int)fy, 0), 62);
                int x0 = min(max((int)fx, 0), 62);
                unsigned r0 = tab2_s[(y0 << 6) + x0];
                unsigned r1 = tab2_s[((y0 + 1) << 6) + x0];
                float r00 = __uint_as_float(r0 << 16);
                float r01 = __uint_as_float(r0 & 0xffff0000u);
                float r10 = __uint_as_float(r1 << 16);
                float r11 = __uint_as_float(r1 & 0xffff0000u);
                float bx0 = r00 + wx * (r01 - r00);
                float bx1 = r10 + wx * (r11 - r10);
                float p = exp2f(sacc[jt][reg] + (bx0 + wy * (bx1 - bx0)));
                pa[(wv * 16 + quad * 4 + reg) * 72 + jt * 16 + l15] = f2bf(p);
            }
        }
        // ---- PV + denom (wave-private P roundtrip, no barrier) ----
        const ush* pbase = pa + (wv * 16 + l15) * 72 + quad * 8;
        shortx8 pf0 = *(const shortx8*)pbase;
        shortx8 pf1 = *(const shortx8*)(pbase + 32);
        o_sum = __builtin_amdgcn_mfma_f32_16x16x32_bf16(pf0, vone, o_sum, 0, 0, 0);
        o_sum = __builtin_amdgcn_mfma_f32_16x16x32_bf16(pf1, vone, o_sum, 0, 0, 0);
        #pragma unroll
        for (int dt = 0; dt < 4; ++dt) {
            o_acc[dt] = __builtin_amdgcn_mfma_f32_16x16x32_bf16(pf0, vf0[dt], o_acc[dt], 0, 0, 0);
            o_acc[dt] = __builtin_amdgcn_mfma_f32_16x16x32_bf16(pf1, vf1[dt], o_acc[dt], 0, 0, 0);
        }
    }

    // ---- epilogue: divide by denom, transpose via LDS (bf16), coalesced store ----
    __syncthreads();
    float inv[4];
    #pragma unroll
    for (int reg = 0; reg < 4; ++reg) inv[reg] = 1.f / o_sum[reg];
    #pragma unroll
    for (int dt = 0; dt < 4; ++dt)
        #pragma unroll
        for (int reg = 0; reg < 4; ++reg)
            obuf[(dt * 16 + l15) * 136 + wv * 16 + quad * 4 + reg] = f2bf(o_acc[dt][reg] * inv[reg]);
    __syncthreads();
    ush* aobase = ao + ((size_t)(b * 512 + h * 64)) * 4096 + m0;
    for (int i = tid; i < 8192; i += 512) {
        int d = i >> 7, m = i & 127;
        aobase[(size_t)d * 4096 + m] = obuf[d * 136 + m];
    }
}

// ---------------------------------------------------------------------------
extern "C" void kernel_launch(void* const* d_in, const int* in_sizes, int n_in,
                              void* d_out, int out_size, void* d_ws, size_t ws_size,
                              hipStream_t stream) {
    const float* x      = (const float*)d_in[0];
    const float* q_w    = (const float*)d_in[1];
    const float* q_b    = (const float*)d_in[2];
    const float* kv_w   = (const float*)d_in[3];
    const float* kv_b   = (const float*)d_in[4];
    const float* off1_w = (const float*)d_in[5];
    const float* off1_b = (const float*)d_in[6];
    const float* gn_w   = (const float*)d_in[7];
    const float* gn_b   = (const float*)d_in[8];
    const float* off2_w = (const float*)d_in[9];
    const float* rpe    = (const float*)d_in[10];
    const float* proj_w = (const float*)d_in[11];
    const float* proj_b = (const float*)d_in[12];

    float* ws   = (float*)d_ws;
    ush*   qT   = (ush*)(ws + OFF_QT);
    float* t    = ws + OFF_T;
    float* gs   = ws + OFF_GS;
    float* pos  = ws + OFF_POS;
    ush*   kT   = (ush*)(ws + OFF_KT);
    ush*   vv   = (ush*)(ws + OFF_VV);
    ush*   smp  = (ush*)(ws + OFF_SMP);
    float* weff = ws + OFF_WEFF;
    float* beff = ws + OFF_BEFF;
    float* part = ws + OFF_PART;
    ush*   ao   = (ush*)(ws + OFF_AO);
    float* out  = (float*)d_out;

    // W_eff = off1_w ∘ q_w (GEMV, fp32), bias_eff
    weff_k<<<dim3(2, 128), 256, 0, stream>>>(off1_w, q_w, weff);
    biaseff_k<<<512, 256, 0, stream>>>(off1_w, off1_b, q_b, beff);
    // qT = bf16(q_w·x + q_b) transposed+scaled
    gemm_mfma_k<1, 0, 5><<<dim3(64, 4, 2), 256, 0, stream>>>(q_w, x, q_b, qT, nullptr, 512, 512, 4096, 1);
    // t = W_eff ⊛ im2col(x): bf16x3, split-K=4
    gemm_mfma_k<3, 1, 2><<<dim3(16, 4, 8), 256, 0, stream>>>(weff, x, nullptr, part, nullptr, 512, 2048, 1024, 4);
    reduce_off1_k<<<4096, 256, 0, stream>>>(part, beff, t);
    // GroupNorm + GELU
    gn_stats_k<<<64, 256, 0, stream>>>(t, gs);
    gn_gelu_k<<<4096, 256, 0, stream>>>(t, gs, gn_w, gn_b);
    // offsets -> sampling positions (fp32)
    offset_pos_k<<<64, 256, 0, stream>>>(t, off2_w, pos);
    // bilinear sample -> bf16
    sample_k<<<4096, 256, 0, stream>>>(x, pos, smp);
    // kv = 1x1 conv(sampled): plain bf16 -> kT (transposed) + vv
    gemm_mfma_k<1, 2, 4><<<dim3(16, 8, 2), 256, 0, stream>>>(kv_w, smp, kv_b, kT, vv, 1024, 512, 1024, 1);
    // fused MFMA flash attention -> bf16 ao  (part dead; ao aliases it)
    attn_k<<<dim3(32, 16), 512, 0, stream>>>(qT, kT, vv, pos, rpe, ao);
    // final projection: plain bf16, fp32 out
    gemm_mfma_k<1, 2, 0><<<dim3(64, 4, 2), 256, 0, stream>>>(proj_w, ao, proj_b, out, nullptr, 512, 512, 4096, 1);
}